// Round 3
// baseline (256.299 us; speedup 1.0000x reference)
//
#include <hip/hip_runtime.h>

// Problem constants (from reference setup_inputs): B=8, H=512, W=512, C=16.
// dense_image_warp: out[b,h,w,c] = bilinear(img, h - flow[b,h,w,0], w - flow[b,h,w,1])
// tfa semantics: floor clipped to [0, size-2], alpha clipped to [0,1].

constexpr int B = 8;
constexpr int H = 512;
constexpr int W = 512;
constexpr int C = 16;
constexpr int P = B * H * W;        // 2,097,152 pixels
constexpr int HALF_P = P / 2;       // each thread handles pixel q and q+HALF_P

// Native clang vector types — required by __builtin_nontemporal_* (HIP's
// float2/float4 are classes and are rejected by the builtin).
typedef float vf2 __attribute__((ext_vector_type(2)));
typedef float vf4 __attribute__((ext_vector_type(4)));

// 4 lanes per pixel (vf4 of channels each), 2 pixels per thread for MLP:
// both flow loads issue first, then all 8 corner gathers, then the blends.
// Latency-bound kernel -> double the outstanding loads per wave.
__global__ __launch_bounds__(256, 8) void warp_kernel(
    const float* __restrict__ img,
    const float* __restrict__ flow,
    float* __restrict__ out)
{
    const int tid = blockIdx.x * blockDim.x + threadIdx.x;
    const int lane = tid & 3;           // channel quad: 0..3
    const int q   = tid >> 2;           // pixel index in [0, HALF_P)
    const int c0  = lane << 2;

    const int p0 = q;
    const int p1 = q + HALF_P;

    // ---- issue both flow loads (read-once -> nontemporal) ----
    const vf2 f0 = __builtin_nontemporal_load(
        reinterpret_cast<const vf2*>(flow + 2 * (size_t)p0));
    const vf2 f1 = __builtin_nontemporal_load(
        reinterpret_cast<const vf2*>(flow + 2 * (size_t)p1));

    // ---- addresses for pixel 0 ----
    const int w0 = p0 & (W - 1);
    const int h0 = (p0 >> 9) & (H - 1);
    const int b0 = p0 >> 18;
    const float qy0 = (float)h0 - f0.x;
    const float qx0 = (float)w0 - f0.y;
    const float fy0 = fminf(fmaxf(floorf(qy0), 0.0f), (float)(H - 2));
    const float fx0 = fminf(fmaxf(floorf(qx0), 0.0f), (float)(W - 2));
    const float ay0 = fminf(fmaxf(qy0 - fy0, 0.0f), 1.0f);
    const float ax0 = fminf(fmaxf(qx0 - fx0, 0.0f), 1.0f);
    const int iy0 = (int)fy0;
    const int ix0 = (int)fx0;

    // ---- addresses for pixel 1 ----
    const int w1 = p1 & (W - 1);
    const int h1 = (p1 >> 9) & (H - 1);
    const int b1 = p1 >> 18;
    const float qy1 = (float)h1 - f1.x;
    const float qx1 = (float)w1 - f1.y;
    const float fy1 = fminf(fmaxf(floorf(qy1), 0.0f), (float)(H - 2));
    const float fx1 = fminf(fmaxf(floorf(qx1), 0.0f), (float)(W - 2));
    const float ay1 = fminf(fmaxf(qy1 - fy1, 0.0f), 1.0f);
    const float ax1 = fminf(fmaxf(qx1 - fx1, 0.0f), 1.0f);
    const int iy1 = (int)fy1;
    const int ix1 = (int)fx1;

    const size_t rowStride = (size_t)W * C;
    const float* base0 = img + ((size_t)((b0 * H + iy0) * W + ix0) * C + c0);
    const float* base1 = img + ((size_t)((b1 * H + iy1) * W + ix1) * C + c0);

    // ---- issue all 8 gathers before any use ----
    const vf4 tl0 = *reinterpret_cast<const vf4*>(base0);
    const vf4 tr0 = *reinterpret_cast<const vf4*>(base0 + C);
    const vf4 bl0 = *reinterpret_cast<const vf4*>(base0 + rowStride);
    const vf4 br0 = *reinterpret_cast<const vf4*>(base0 + rowStride + C);
    const vf4 tl1 = *reinterpret_cast<const vf4*>(base1);
    const vf4 tr1 = *reinterpret_cast<const vf4*>(base1 + C);
    const vf4 bl1 = *reinterpret_cast<const vf4*>(base1 + rowStride);
    const vf4 br1 = *reinterpret_cast<const vf4*>(base1 + rowStride + C);

    // ---- blends (reference operation order, elementwise on vectors) ----
    const vf4 t0v = tl0 + ax0 * (tr0 - tl0);
    const vf4 b0v = bl0 + ax0 * (br0 - bl0);
    const vf4 o0  = t0v + ay0 * (b0v - t0v);

    const vf4 t1v = tl1 + ax1 * (tr1 - tl1);
    const vf4 b1v = bl1 + ax1 * (br1 - bl1);
    const vf4 o1  = t1v + ay1 * (b1v - t1v);

    // ---- stores: write-once stream -> nontemporal, coalesced ----
    __builtin_nontemporal_store(
        o0, reinterpret_cast<vf4*>(out + (size_t)p0 * C + c0));
    __builtin_nontemporal_store(
        o1, reinterpret_cast<vf4*>(out + (size_t)p1 * C + c0));
}

extern "C" void kernel_launch(void* const* d_in, const int* in_sizes, int n_in,
                              void* d_out, int out_size, void* d_ws, size_t ws_size,
                              hipStream_t stream) {
    const float* img  = (const float*)d_in[0];   // [B,H,W,C] fp32
    const float* flow = (const float*)d_in[1];   // [B,H,W,2] fp32
    float* out = (float*)d_out;                  // [B,H,W,C] fp32

    // total threads = P*4/2 = 4,194,304 -> exact fit
    const int total = HALF_P * 4;
    const int block = 256;
    const int grid = total / block;  // 16384
    warp_kernel<<<grid, block, 0, stream>>>(img, flow, out);
}